// Round 4
// baseline (356.055 us; speedup 1.0000x reference)
//
#include <hip/hip_runtime.h>

#define D 128
#define TD 384  // 3*D

// -------- K_prep: p[t] = sum_i v[i] * A[i*384 + t]  (ps|pd|pr concatenated) ----
__global__ void k_prep(const float* __restrict__ A, const float* __restrict__ v,
                       float* __restrict__ p) {
  __shared__ float vs[D];
  int t = threadIdx.x;
  if (t < D) vs[t] = v[t];
  __syncthreads();
  float acc = 0.f;
#pragma unroll 8
  for (int i = 0; i < D; ++i) acc += vs[i] * A[i * TD + t];
  p[t] = acc;
}

// -------- K_scores + histogram (fused): wave-per-node dot products; extra blocks
// do the dst histogram for the CSR build. ------------------------------------
__global__ void k_scores_hist(const float* __restrict__ h, const float* __restrict__ emb,
                              const float* __restrict__ p, const int* __restrict__ dst,
                              float* __restrict__ ss, float* __restrict__ sd,
                              float* __restrict__ sr, int* __restrict__ cnt,
                              int N, int R, int E, int nbScore) {
  int t = threadIdx.x;
  if ((int)blockIdx.x < nbScore) {
    __shared__ float pl[TD];
    pl[t] = p[t];
    if (t < TD - 256) pl[256 + t] = p[256 + t];
    __syncthreads();
    int w = blockIdx.x * 4 + (t >> 6);
    int l = t & 63;
    if (w < N) {
      float x0 = h[(size_t)w * D + l];
      float x1 = h[(size_t)w * D + 64 + l];
      float a = x0 * pl[l] + x1 * pl[64 + l];
      float b = x0 * pl[128 + l] + x1 * pl[192 + l];
#pragma unroll
      for (int o = 32; o; o >>= 1) { a += __shfl_xor(a, o); b += __shfl_xor(b, o); }
      if (l == 0) { ss[w] = a; sd[w] = b; }
    } else if (w < N + R) {
      int r = w - N;
      float x0 = emb[(size_t)r * D + l];
      float x1 = emb[(size_t)r * D + 64 + l];
      float c = x0 * pl[256 + l] + x1 * pl[320 + l];
#pragma unroll
      for (int o = 32; o; o >>= 1) c += __shfl_xor(c, o);
      if (l == 0) sr[r] = c;
    }
  } else {
    int i = (blockIdx.x - nbScore) * 256 + t;
    int stride = (gridDim.x - nbScore) * 256;
    for (; i < E; i += stride) atomicAdd(&cnt[dst[i]], 1);
  }
}

// -------- 3-phase exclusive scan of cnt[0..N-1] ------------------------------
__global__ void k_scan1(int* __restrict__ cnt, int* __restrict__ bsum, int N) {
  __shared__ int wsum[16];
  int t = threadIdx.x, lane = t & 63, wid = t >> 6;
  int i = blockIdx.x * 1024 + t;
  int v = (i < N) ? cnt[i] : 0;
  int x = v;
#pragma unroll
  for (int o = 1; o < 64; o <<= 1) {
    int y = __shfl_up(x, o);
    if (lane >= o) x += y;
  }
  if (lane == 63) wsum[wid] = x;
  __syncthreads();
  if (t < 16) {
    int y = wsum[t];
#pragma unroll
    for (int o = 1; o < 16; o <<= 1) {
      int z = __shfl_up(y, o);
      if (t >= o) y += z;
    }
    wsum[t] = y;
  }
  __syncthreads();
  int woff = wid ? wsum[wid - 1] : 0;
  if (i < N) cnt[i] = woff + x - v;     // block-local exclusive scan
  if (t == 0) bsum[blockIdx.x] = wsum[15];
}

__global__ void k_scan2(int* __restrict__ bsum, int nsb) {
  int l = threadIdx.x;
  int v = (l < nsb) ? bsum[l] : 0;
  int x = v;
#pragma unroll
  for (int o = 1; o < 64; o <<= 1) {
    int y = __shfl_up(x, o);
    if (l >= o) x += y;
  }
  if (l < nsb) bsum[l] = x - v;          // exclusive block offsets, in place
}

__global__ void k_scan3(const int* __restrict__ bsum, int* __restrict__ cnt,
                        int* __restrict__ cur, int N, int E) {
  int i = blockIdx.x * 1024 + threadIdx.x;
  if (i < N) {
    int v = cnt[i] + bsum[blockIdx.x];
    cnt[i] = v;
    cur[i] = v;
  }
  if (i == 0) cnt[N] = E;
}

// -------- K_edge: per-edge logit + scatter into dst-sorted order --------------
__global__ void k_edge(const int* __restrict__ src, const int* __restrict__ dst,
                       const int* __restrict__ et, const float* __restrict__ ss,
                       const float* __restrict__ sd, const float* __restrict__ sr,
                       int* __restrict__ cur, float* __restrict__ esort,
                       int* __restrict__ ssort, int E) {
  int i = blockIdx.x * blockDim.x + threadIdx.x;
  if (i >= E) return;
  int s = src[i], d = dst[i], r = et[i];
  float e = ss[s] + sd[d] + sr[r];
  e = (e > 0.f) ? e : 0.01f * e;
  int pos = atomicAdd(&cur[d], 1);
  esort[pos] = e;
  ssort[pos] = s;
}

// -------- K_agg: one 256-thread block per dst node. Layout: thread = (slot,qc),
// slot=t>>5 in [0,8) strides over edges, qc=t&31 covers column quad 4*qc..4*qc+3.
// One global_load_dwordx4 wave-instr gathers 2 edges' half-KB rows -> 4x fewer
// memory instrs than scalar thread-per-column. Weights recomputed in-register
// (exp is cheap), partials tree-reduced through 4KB LDS once per node. --------
__global__ __launch_bounds__(256) void k_agg(const float* __restrict__ h,
                                             const int* __restrict__ off,
                                             const float* __restrict__ esort,
                                             const int* __restrict__ ssort,
                                             float* __restrict__ out, int N) {
  int n = blockIdx.x;
  int t = threadIdx.x;
  int start = off[n], deg = off[n + 1] - start;
  int qc = t & 31;        // column quad
  int slot = t >> 5;      // edge slot 0..7
  if (deg == 0) {         // block-uniform: DGL keeps h unchanged
    if (slot == 0)
      ((float4*)(out + (size_t)n * D))[qc] = ((const float4*)(h + (size_t)n * D))[qc];
    return;
  }
  __shared__ float4 part[8][32];
  __shared__ float dpart[8];
  __shared__ float mred[4];

  // pass A: segment max (all 256 threads)
  float m = -3.4e38f;
  for (int i = t; i < deg; i += 256) m = fmaxf(m, esort[start + i]);
#pragma unroll
  for (int o = 32; o; o >>= 1) m = fmaxf(m, __shfl_xor(m, o));
  if ((t & 63) == 0) mred[t >> 6] = m;
  __syncthreads();
  m = fmaxf(fmaxf(mred[0], mred[1]), fmaxf(mred[2], mred[3]));

  // pass B: slot-strided weighted gather, float4 per lane
  float4 acc = {0.f, 0.f, 0.f, 0.f};
  float wpriv = 0.f;
  for (int i = slot; i < deg; i += 8) {
    float w = __expf(esort[start + i] - m);
    int s = ssort[start + i];
    float4 hv = ((const float4*)(h + (size_t)s * D))[qc];
    acc.x = fmaf(w, hv.x, acc.x);
    acc.y = fmaf(w, hv.y, acc.y);
    acc.z = fmaf(w, hv.z, acc.z);
    acc.w = fmaf(w, hv.w, acc.w);
    wpriv += w;
  }
  part[slot][qc] = acc;
  if (qc == 0) dpart[slot] = wpriv;
  __syncthreads();
  if (slot == 0) {
    float4 s4 = part[0][qc];
#pragma unroll
    for (int s2 = 1; s2 < 8; ++s2) {
      float4 p4 = part[s2][qc];
      s4.x += p4.x; s4.y += p4.y; s4.z += p4.z; s4.w += p4.w;
    }
    float denom = ((dpart[0] + dpart[1]) + (dpart[2] + dpart[3])) +
                  ((dpart[4] + dpart[5]) + (dpart[6] + dpart[7]));
    float inv = 1.f / denom;
    float4 r;
    r.x = s4.x * inv; r.y = s4.y * inv; r.z = s4.z * inv; r.w = s4.w * inv;
    ((float4*)(out + (size_t)n * D))[qc] = r;
  }
}

// -------- K_final: out += h @ loop_weight. W column pinned in VGPRs via an
// opaque-asm barrier (compiler cannot rematerialize an asm result, so no W
// re-loads in the n-loop -- round-3's 82us was exactly that L2 traffic).
// h rows read via wave-uniform addresses; 2 nodes/iter -> 8 indep FMA chains.
__global__ __launch_bounds__(128, 2) void k_final(const float* __restrict__ h,
                                                  const float* __restrict__ lw,
                                                  float* __restrict__ out, int N) {
  int j = threadIdx.x;                  // output column, 0..127
  float w[D];                           // W[:, j] pinned in registers
#pragma unroll
  for (int k = 0; k < D; ++k) w[k] = lw[(size_t)k * D + j];
#pragma unroll
  for (int k = 0; k < D; ++k) asm volatile("" : "+v"(w[k]));  // pin: no remat

  int stride = gridDim.x;
  for (int n = blockIdx.x; n < N; n += 2 * stride) {
    int n2 = n + stride;
    const float4* __restrict__ ra = (const float4*)(h + (size_t)n * D);
    float a0 = 0.f, a1 = 0.f, a2 = 0.f, a3 = 0.f;
    float b0 = 0.f, b1 = 0.f, b2 = 0.f, b3 = 0.f;
    if (n2 < N) {
      const float4* __restrict__ rb = (const float4*)(h + (size_t)n2 * D);
#pragma unroll
      for (int q = 0; q < D / 4; ++q) {
        float4 va = ra[q];
        float4 vb = rb[q];
        a0 = fmaf(va.x, w[4 * q + 0], a0);
        a1 = fmaf(va.y, w[4 * q + 1], a1);
        a2 = fmaf(va.z, w[4 * q + 2], a2);
        a3 = fmaf(va.w, w[4 * q + 3], a3);
        b0 = fmaf(vb.x, w[4 * q + 0], b0);
        b1 = fmaf(vb.y, w[4 * q + 1], b1);
        b2 = fmaf(vb.z, w[4 * q + 2], b2);
        b3 = fmaf(vb.w, w[4 * q + 3], b3);
      }
      out[(size_t)n * D + j] += (a0 + a1) + (a2 + a3);
      out[(size_t)n2 * D + j] += (b0 + b1) + (b2 + b3);
    } else {
#pragma unroll
      for (int q = 0; q < D / 4; ++q) {
        float4 va = ra[q];
        a0 = fmaf(va.x, w[4 * q + 0], a0);
        a1 = fmaf(va.y, w[4 * q + 1], a1);
        a2 = fmaf(va.z, w[4 * q + 2], a2);
        a3 = fmaf(va.w, w[4 * q + 3], a3);
      }
      out[(size_t)n * D + j] += (a0 + a1) + (a2 + a3);
    }
  }
}

extern "C" void kernel_launch(void* const* d_in, const int* in_sizes, int n_in,
                              void* d_out, int out_size, void* d_ws, size_t ws_size,
                              hipStream_t stream) {
  const float* h   = (const float*)d_in[0];
  const float* emb = (const float*)d_in[1];
  const float* lw  = (const float*)d_in[2];
  const float* afw = (const float*)d_in[3];
  const float* af2 = (const float*)d_in[4];
  const int* src = (const int*)d_in[5];
  const int* dst = (const int*)d_in[6];
  const int* et  = (const int*)d_in[7];
  int N = in_sizes[0] / D;
  int R = in_sizes[1] / D;
  int E = in_sizes[5];
  float* out = (float*)d_out;

  char* ws = (char*)d_ws;
  size_t o = 0;
  auto alloc = [&](size_t bytes) -> void* {
    void* pp = ws + o;
    o = (o + bytes + 255) & ~(size_t)255;
    return pp;
  };
  float* p     = (float*)alloc((size_t)TD * 4);
  float* ss    = (float*)alloc((size_t)N * 4);
  float* sd    = (float*)alloc((size_t)N * 4);
  float* srel  = (float*)alloc((size_t)R * 4);
  int*   cnt   = (int*)  alloc((size_t)(N + 1) * 4);
  int*   cur   = (int*)  alloc((size_t)N * 4);
  int*   bsum  = (int*)  alloc((size_t)64 * 4);
  float* esort = (float*)alloc((size_t)E * 4);
  int*   ssort = (int*)  alloc((size_t)E * 4);

  int nsb = (N + 1023) / 1024;          // 49 for N=50000 (<= 64 for scan2 wave)

  hipMemsetAsync(cnt, 0, (size_t)(N + 1) * 4, stream);
  k_prep<<<1, TD, 0, stream>>>(afw, af2, p);
  int nbScore = (N + R + 3) / 4;
  int nbHist = 2048;
  k_scores_hist<<<nbScore + nbHist, 256, 0, stream>>>(h, emb, p, dst, ss, sd, srel,
                                                      cnt, N, R, E, nbScore);
  k_scan1<<<nsb, 1024, 0, stream>>>(cnt, bsum, N);
  k_scan2<<<1, 64, 0, stream>>>(bsum, nsb);
  k_scan3<<<nsb, 1024, 0, stream>>>(bsum, cnt, cur, N, E);
  k_edge<<<(E + 255) / 256, 256, 0, stream>>>(src, dst, et, ss, sd, srel, cur,
                                              esort, ssort, E);
  k_agg<<<N, 256, 0, stream>>>(h, cnt, esort, ssort, out, N);
  k_final<<<1024, 128, 0, stream>>>(h, lw, out, N);
}